// Round 7
// baseline (2076.603 us; speedup 1.0000x reference)
//
#include <hip/hip_runtime.h>

namespace {

constexpr int B = 32, H = 512, L = 2, T = 20, V = 10000, S = 49;

__device__ __forceinline__ float sigf(float x) { return 1.0f / (1.0f + expf(-x)); }
__device__ __forceinline__ float dot4(float4 a, float4 b) {
  return a.x*b.x + a.y*b.y + a.z*b.z + a.w*b.w;
}

// ---------------- setup: kv (blocks 0..255) + init (256..383) + slog[0] (384..1008)
__global__ __launch_bounds__(256) void setup_kernel(
    const float* __restrict__ chan,
    const float* __restrict__ Wk, const float* __restrict__ bk,
    const float* __restrict__ Wv, const float* __restrict__ bv,
    float* __restrict__ keysT, float* __restrict__ valuesT,
    const float* __restrict__ pooled, const float* __restrict__ embed,
    const int* __restrict__ sos,
    float* __restrict__ emb, float* __restrict__ h, float* __restrict__ c,
    const float* __restrict__ projW, const float* __restrict__ projb,
    float* __restrict__ slog0) {
  __shared__ __align__(16) float smem[8448];
  int blk = blockIdx.x, tid = threadIdx.x;
  if (blk < 256) {
    // ---- kv: verbatim kv_kernel body ----
    float* ch = smem;                 // 64*52
    float* wk = smem + 64 * 52;       // 49*52
    float* wv = wk + 49 * 52;         // 49*52
    int b = blk >> 3, dt = blk & 7;
    for (int i = tid; i < 49 * 49; i += 256) {
      int s = i / 49, j = i % 49;
      wk[s * 52 + j] = Wk[i]; wv[s * 52 + j] = Wv[i];
    }
    for (int i = tid; i < 64 * 49; i += 256) {
      int d = i / 49, j = i % 49;
      ch[d * 52 + j] = chan[((size_t)b * 512 + dt * 64 + d) * S + j];
    }
    __syncthreads();
    int dl = tid >> 2, sq = tid & 3;
    for (int s = sq; s < S; s += 4) {
      float ak = bk[s], av = bv[s];
      for (int j = 0; j < 49; ++j) {
        float cv = ch[dl * 52 + j];
        ak += cv * wk[s * 52 + j];
        av += cv * wv[s * 52 + j];
      }
      int d = dt * 64 + dl;
      keysT[((size_t)b * S + s) * H + d] = tanhf(ak);
      valuesT[((size_t)b * S + s) * H + d] = tanhf(av);
    }
  } else if (blk < 384) {
    // ---- init: verbatim init_kernel body ----
    int idx = (blk - 256) * 256 + tid;      // [0, 32768)
    float p = pooled[idx & (B * H - 1)];
    h[idx] = p;
    c[idx] = p;
    if (idx < B * H) emb[idx] = embed[(size_t)sos[0] * H + (idx & (H - 1))];
  } else {
    // ---- slog[0] = proj(embed[sos]) : batch-independent ----
    float* es = smem;                 // 512
    es[tid] = embed[(size_t)sos[0] * H + tid];
    es[tid + 256] = embed[(size_t)sos[0] * H + tid + 256];
    __syncthreads();
    int ko = tid & 15, vl = tid >> 4;
    int v = (blk - 384) * 16 + vl;
    const float* wrow = projW + (size_t)v * H;
    float4 w[8];
#pragma unroll
    for (int kk = 0; kk < 8; ++kk) w[kk] = *(const float4*)&wrow[kk * 64 + ko * 4];
    float acc = 0.f;
#pragma unroll
    for (int kk = 0; kk < 8; ++kk)
      acc += dot4(*(const float4*)&es[kk * 64 + ko * 4], w[kk]);
    acc += __shfl_xor(acc, 1);
    acc += __shfl_xor(acc, 2);
    acc += __shfl_xor(acc, 4);
    acc += __shfl_xor(acc, 8);
    if (ko == 0) {
      float r = acc + projb[v];
      for (int b = 0; b < 32; ++b) slog0[(size_t)b * V + v] = r;
    }
  }
}

// ---------------- LSTM cell: 16 KB LDS (4 chunks of 8 batches) -----------
// Per-output fp sequence identical to the verified 64 KB version: acc for
// (gate rr, row hi, batch b) = 8 x-dot4s in kk order, then 8 h-dot4s.
// Thread->batch remap: chunk ch holds batches ch*8..ch*8+7; thread (bh)
// computes batches ch*8 + bh*2 + {0,1}.
__global__ __launch_bounds__(256) void lstm_kernel(
    const float* __restrict__ x, const float* __restrict__ hprev,
    const float* __restrict__ cprev,
    const float* __restrict__ Wih, const float* __restrict__ Whh,
    const float* __restrict__ bih, const float* __restrict__ bhh,
    float* __restrict__ hout, float* __restrict__ cout) {
  __shared__ __align__(16) float smem[8 * 512];   // 16 KB
  int tid = threadIdx.x;
  int hi = blockIdx.x;
  int ko = tid & 15, rr = (tid >> 4) & 3, bh = tid >> 6;
  float acc[8];
#pragma unroll
  for (int a = 0; a < 8; ++a) acc[a] = 0.f;
  float4 w[8];
  {
    const float* wrow = Wih + ((size_t)rr * H + hi) * H;
#pragma unroll
    for (int kk = 0; kk < 8; ++kk) w[kk] = *(const float4*)&wrow[kk * 64 + ko * 4];
  }
  // phase 1: x @ Wih^T
  for (int ch = 0; ch < 4; ++ch) {
    {
      const float4* xg = (const float4*)x + ch * 1024;
      float4* s4 = (float4*)smem;
      for (int i = tid; i < 1024; i += 256) s4[i] = xg[i];
    }
    __syncthreads();
#pragma unroll
    for (int jj = 0; jj < 2; ++jj) {
      const float* xb = smem + (bh * 2 + jj) * 512;
      int a = ch * 2 + jj;
#pragma unroll
      for (int kk = 0; kk < 8; ++kk)
        acc[a] += dot4(*(const float4*)&xb[kk * 64 + ko * 4], w[kk]);
    }
    __syncthreads();
  }
  {
    const float* wrow = Whh + ((size_t)rr * H + hi) * H;
#pragma unroll
    for (int kk = 0; kk < 8; ++kk) w[kk] = *(const float4*)&wrow[kk * 64 + ko * 4];
  }
  // phase 2: h @ Whh^T
  for (int ch = 0; ch < 4; ++ch) {
    {
      const float4* hg = (const float4*)hprev + ch * 1024;
      float4* s4 = (float4*)smem;
      for (int i = tid; i < 1024; i += 256) s4[i] = hg[i];
    }
    __syncthreads();
#pragma unroll
    for (int jj = 0; jj < 2; ++jj) {
      const float* xb = smem + (bh * 2 + jj) * 512;
      int a = ch * 2 + jj;
#pragma unroll
      for (int kk = 0; kk < 8; ++kk)
        acc[a] += dot4(*(const float4*)&xb[kk * 64 + ko * 4], w[kk]);
    }
    __syncthreads();
  }
#pragma unroll
  for (int a = 0; a < 8; ++a) {
    acc[a] += __shfl_xor(acc[a], 1);
    acc[a] += __shfl_xor(acc[a], 2);
    acc[a] += __shfl_xor(acc[a], 4);
    acc[a] += __shfl_xor(acc[a], 8);
  }
  float* gbuf = smem;   // reuse (128 floats)
  if (ko == 0) {
    float bias = bih[rr * H + hi] + bhh[rr * H + hi];
#pragma unroll
    for (int ch = 0; ch < 4; ++ch)
#pragma unroll
      for (int jj = 0; jj < 2; ++jj)
        gbuf[rr * 32 + ch * 8 + bh * 2 + jj] = acc[ch * 2 + jj] + bias;
  }
  __syncthreads();
  if (tid < 32) {
    int b = tid;
    float gi = gbuf[b], gf = gbuf[32 + b], gg = gbuf[64 + b], go = gbuf[96 + b];
    float c2 = sigf(gf) * cprev[b * H + hi] + sigf(gi) * tanhf(gg);
    hout[b * H + hi] = sigf(go) * tanhf(c2);
    cout[b * H + hi] = c2;
  }
}

// ---------------- fused proj (blocks 0..624, 16 KB chunked) + sattn (625..688)
__global__ __launch_bounds__(256) void projsat_kernel(
    const float* __restrict__ hmid_all,
    const float* __restrict__ projW, const float* __restrict__ projb,
    const float* __restrict__ Wq, const float* __restrict__ bq,
    const float* __restrict__ keysT, const float* __restrict__ valuesT,
    float* __restrict__ dst, float* __restrict__ cat) {
  __shared__ __align__(16) float smem[8 * 512];   // 16 KB
  int blk = blockIdx.x, tid = threadIdx.x;
  if (blk < 625) {
    // ---- proj of top-layer hmid -> dst; per-(v,b) fp sequence verbatim ----
    const float* xin = hmid_all + B * H;
    int ko = tid & 15, vl = tid >> 4;
    int v = blk * 16 + vl;
    const float* wrow = projW + (size_t)v * H;
    float4 w[8];
#pragma unroll
    for (int kk = 0; kk < 8; ++kk) w[kk] = *(const float4*)&wrow[kk * 64 + ko * 4];
    float acc[32];
#pragma unroll
    for (int b = 0; b < 32; ++b) acc[b] = 0.f;
    for (int ch = 0; ch < 4; ++ch) {
      {
        const float4* xg = (const float4*)xin + ch * 1024;
        float4* s4 = (float4*)smem;
        for (int i = tid; i < 1024; i += 256) s4[i] = xg[i];
      }
      __syncthreads();
#pragma unroll
      for (int bl = 0; bl < 8; ++bl) {
        int b = ch * 8 + bl;
        const float* xb = smem + bl * 512;
#pragma unroll
        for (int kk = 0; kk < 8; ++kk)
          acc[b] += dot4(*(const float4*)&xb[kk * 64 + ko * 4], w[kk]);
      }
      __syncthreads();
    }
#pragma unroll
    for (int b = 0; b < 32; ++b) {
      acc[b] += __shfl_xor(acc[b], 1);
      acc[b] += __shfl_xor(acc[b], 2);
      acc[b] += __shfl_xor(acc[b], 4);
      acc[b] += __shfl_xor(acc[b], 8);
    }
    if (ko == 0) {
      float bias = projb[v];
      for (int b = 0; b < 32; ++b) dst[(size_t)b * V + v] = acc[b] + bias;
    }
  } else {
    // ---- sattn for one lb, computing q in-block (verbatim from r6) ----
    int lb = blk - 625;               // 0..63
    int b = lb & 31, lg = lb >> 5;
    float* hr  = smem;                // 512
    float* qv  = smem + 512;          // 528 (4 chunks of 132, +4 skew)
    float* scl = smem + 1040;         // 64
    float* wts = smem + 1104;         // 64
    const float* hrow = hmid_all + (size_t)lg * B * H + (size_t)b * H;
    hr[tid] = hrow[tid];
    hr[tid + 256] = hrow[tid + 256];
    __syncthreads();
    int ko = tid & 15, vl = tid >> 4;
    for (int jg = 0; jg < 32; ++jg) {
      int j = jg * 16 + vl;
      const float* wrow = Wq + (size_t)j * H;
      float4 w[8];
#pragma unroll
      for (int kk = 0; kk < 8; ++kk) w[kk] = *(const float4*)&wrow[kk * 64 + ko * 4];
      float acc = 0.f;
#pragma unroll
      for (int kk = 0; kk < 8; ++kk)
        acc += dot4(*(const float4*)&hr[kk * 64 + ko * 4], w[kk]);
      acc += __shfl_xor(acc, 1);
      acc += __shfl_xor(acc, 2);
      acc += __shfl_xor(acc, 4);
      acc += __shfl_xor(acc, 8);
      if (ko == 0) qv[(j >> 7) * 132 + (j & 127)] = tanhf(acc + bq[j]);
    }
    __syncthreads();
    int kq = tid & 3, sl = tid >> 2;
    float acc = 0.f;
    if (sl < S) {
      const float* kr = keysT + ((size_t)b * S + sl) * H + kq * 128;
      const float* qr = &qv[kq * 132];
      for (int k = 0; k < 128; k += 4)
        acc += dot4(*(const float4*)&qr[k], *(const float4*)&kr[k]);
    }
    acc += __shfl_xor(acc, 1);
    acc += __shfl_xor(acc, 2);
    if (kq == 0 && sl < S) scl[sl] = acc * (1.0f / 7.0f);
    __syncthreads();
    if (tid < 64) {
      float sc = (tid < S) ? scl[tid] : -3.4e38f;
      float m = sc;
      for (int o = 32; o > 0; o >>= 1) m = fmaxf(m, __shfl_xor(m, o));
      float e = (tid < S) ? expf(sc - m) : 0.f;
      float sum = e;
      for (int o = 32; o > 0; o >>= 1) sum += __shfl_xor(sum, o);
      if (tid < S) wts[tid] = e / sum;
    }
    __syncthreads();
    float acc0 = 0.f, acc1 = 0.f;
    for (int s = 0; s < S; ++s) {
      float w = wts[s];
      const float* vr = valuesT + ((size_t)b * S + s) * H;
      acc0 += w * vr[tid];
      acc1 += w * vr[tid + 256];
    }
    cat[lb * 1024 + tid] = acc0;
    cat[lb * 1024 + tid + 256] = acc1;
    cat[lb * 1024 + 512 + tid] = hmid_all[lb * H + tid];
    cat[lb * 1024 + 768 + tid] = hmid_all[lb * H + tid + 256];
  }
}

// ---------------- hatt (0..127, 16 KB chunked) + argmax/embed (128..159) ----
__global__ __launch_bounds__(256) void hattarg_kernel(
    const float* __restrict__ cat, const float* __restrict__ hattW,
    const float* __restrict__ hattb, float* __restrict__ h,
    const float* __restrict__ logits, const float* __restrict__ embed,
    float* __restrict__ emb) {
  __shared__ __align__(16) float smem[4 * 1024];   // 16 KB
  int blk = blockIdx.x, tid = threadIdx.x;
  if (blk < 128) {
    int lbg = blk & 3, jg = blk >> 2;
    int ko = tid & 15, jl = tid >> 4;
    int j = jg * 16 + jl;
    const float* wrow = hattW + (size_t)j * 1024;
    float4 w[16];
#pragma unroll
    for (int kk = 0; kk < 16; ++kk) w[kk] = *(const float4*)&wrow[kk * 64 + ko * 4];
    float acc[16];
#pragma unroll
    for (int lb = 0; lb < 16; ++lb) acc[lb] = 0.f;
    for (int ch = 0; ch < 4; ++ch) {
      {
        const float4* cg2 = (const float4*)(cat + lbg * 16 * 1024) + ch * 1024;
        float4* s4 = (float4*)smem;
        for (int i = tid; i < 1024; i += 256) s4[i] = cg2[i];
      }
      __syncthreads();
#pragma unroll
      for (int ll = 0; ll < 4; ++ll) {
        int lb = ch * 4 + ll;
        const float* cb = smem + ll * 1024;
#pragma unroll
        for (int kk = 0; kk < 16; ++kk)
          acc[lb] += dot4(*(const float4*)&cb[kk * 64 + ko * 4], w[kk]);
      }
      __syncthreads();
    }
#pragma unroll
    for (int lb = 0; lb < 16; ++lb) {
      acc[lb] += __shfl_xor(acc[lb], 1);
      acc[lb] += __shfl_xor(acc[lb], 2);
      acc[lb] += __shfl_xor(acc[lb], 4);
      acc[lb] += __shfl_xor(acc[lb], 8);
    }
    if (ko == 0) {
      float bias = hattb[j];
      for (int lb = 0; lb < 16; ++lb)
        h[(lbg * 16 + lb) * H + j] = tanhf(acc[lb] + bias);
    }
  } else {
    int b = blk - 128;
    float* sv = smem;
    int* si = (int*)(smem + 256);
    float best = -3.4e38f;
    int bi = 0x7fffffff;
    for (int it = 0; it < 10; ++it) {
      int v0 = it * 1024 + tid * 4;
      if (v0 < V) {
        float4 lv = *(const float4*)&logits[(size_t)b * V + v0];
        if (lv.x > best) { best = lv.x; bi = v0; }
        if (lv.y > best) { best = lv.y; bi = v0 + 1; }
        if (lv.z > best) { best = lv.z; bi = v0 + 2; }
        if (lv.w > best) { best = lv.w; bi = v0 + 3; }
      }
    }
    sv[tid] = best; si[tid] = bi;
    __syncthreads();
    for (int st = 128; st > 0; st >>= 1) {
      if (tid < st) {
        float ov = sv[tid + st]; int oi = si[tid + st];
        if (ov > sv[tid] || (ov == sv[tid] && oi < si[tid])) { sv[tid] = ov; si[tid] = oi; }
      }
      __syncthreads();
    }
    int idx = si[0];
    for (int i = tid; i < H; i += 256) emb[b * H + i] = embed[(size_t)idx * H + i];
  }
}

// ---------------- final transpose: slog[t][b][v] -> out[b][v][t] ----------
__global__ __launch_bounds__(256) void finalize_kernel(
    const float* __restrict__ slog, float* __restrict__ outp) {
  int idx = blockIdx.x * 256 + threadIdx.x;   // b*V + v, exact 320000
  float vals[T];
#pragma unroll
  for (int t = 0; t < T; ++t) vals[t] = slog[(size_t)t * (B * V) + idx];
#pragma unroll
  for (int t = 0; t < T; t += 4)
    *(float4*)&outp[(size_t)idx * T + t] =
        make_float4(vals[t], vals[t + 1], vals[t + 2], vals[t + 3]);
}

// ============ fallback kernels (non-staged workspace): verified baseline =====

__global__ __launch_bounds__(256) void kv_kernel(
    const float* __restrict__ chan,
    const float* __restrict__ Wk, const float* __restrict__ bk,
    const float* __restrict__ Wv, const float* __restrict__ bv,
    float* __restrict__ keysT, float* __restrict__ valuesT) {
  __shared__ float ch[64][52];
  __shared__ float wk[49][52], wv[49][52];
  int b = blockIdx.x >> 3, dt = blockIdx.x & 7;
  int tid = threadIdx.x;
  for (int i = tid; i < 49 * 49; i += 256) {
    int s = i / 49, j = i % 49;
    wk[s][j] = Wk[i]; wv[s][j] = Wv[i];
  }
  for (int i = tid; i < 64 * 49; i += 256) {
    int d = i / 49, j = i % 49;
    ch[d][j] = chan[((size_t)b * 512 + dt * 64 + d) * S + j];
  }
  __syncthreads();
  int dl = tid >> 2, sq = tid & 3;
  for (int s = sq; s < S; s += 4) {
    float ak = bk[s], av = bv[s];
    for (int j = 0; j < 49; ++j) {
      float cv = ch[dl][j];
      ak += cv * wk[s][j];
      av += cv * wv[s][j];
    }
    int d = dt * 64 + dl;
    keysT[((size_t)b * S + s) * H + d] = tanhf(ak);
    valuesT[((size_t)b * S + s) * H + d] = tanhf(av);
  }
}

__global__ void init_kernel(const float* __restrict__ pooled,
                            const float* __restrict__ embed,
                            const int* __restrict__ sos,
                            float* __restrict__ emb, float* __restrict__ h,
                            float* __restrict__ c) {
  int idx = blockIdx.x * 256 + threadIdx.x;
  float p = pooled[idx & (B * H - 1)];
  h[idx] = p;
  c[idx] = p;
  if (idx < B * H) emb[idx] = embed[sos[0] * H + (idx & (H - 1))];
}

__global__ __launch_bounds__(256) void projq_kernel(
    const float* __restrict__ xin,
    const float* __restrict__ projW, const float* __restrict__ projb,
    float* __restrict__ logits, float* __restrict__ ocol, int direct, int tcol,
    const float* __restrict__ hmid_all, const float* __restrict__ Wq,
    const float* __restrict__ bq, float* __restrict__ q) {
  __shared__ __align__(16) float xs[32 * 512];
  int blk = blockIdx.x, tid = threadIdx.x;
  int ko = tid & 15, vl = tid >> 4;
  if (blk < 625) {
    {
      const float4* xg = (const float4*)xin;
      float4* s4 = (float4*)xs;
      for (int i = tid; i < 4096; i += 256) s4[i] = xg[i];
    }
    __syncthreads();
    int v = blk * 16 + vl;
    const float* wrow = projW + (size_t)v * H;
    float4 w[8];
#pragma unroll
    for (int kk = 0; kk < 8; ++kk) w[kk] = *(const float4*)&wrow[kk * 64 + ko * 4];
    float acc[32];
#pragma unroll
    for (int b = 0; b < 32; ++b) acc[b] = 0.f;
    for (int b = 0; b < 32; ++b) {
      const float* xb = xs + b * 512;
#pragma unroll
      for (int kk = 0; kk < 8; ++kk)
        acc[b] += dot4(*(const float4*)&xb[kk * 64 + ko * 4], w[kk]);
    }
#pragma unroll
    for (int b = 0; b < 32; ++b) {
      acc[b] += __shfl_xor(acc[b], 1);
      acc[b] += __shfl_xor(acc[b], 2);
      acc[b] += __shfl_xor(acc[b], 4);
      acc[b] += __shfl_xor(acc[b], 8);
    }
    if (ko == 0) {
      float bias = projb[v];
      for (int b = 0; b < 32; ++b) {
        float r = acc[b] + bias;
        logits[b * V + v] = r;
        if (direct) ocol[((size_t)b * V + v) * T + tcol] = r;
        else        ocol[b * V + v] = r;
      }
    }
  } else {
    int b2 = blk - 625;
    int lg = b2 & 1, jg = b2 >> 1;
    {
      const float4* xg = (const float4*)(hmid_all + lg * 32 * H);
      float4* s4 = (float4*)xs;
      for (int i = tid; i < 4096; i += 256) s4[i] = xg[i];
    }
    __syncthreads();
    int j = jg * 16 + vl;
    const float* wrow = Wq + (size_t)j * H;
    float4 w[8];
#pragma unroll
    for (int kk = 0; kk < 8; ++kk) w[kk] = *(const float4*)&wrow[kk * 64 + ko * 4];
    float acc[32];
#pragma unroll
    for (int b = 0; b < 32; ++b) acc[b] = 0.f;
    for (int b = 0; b < 32; ++b) {
      const float* xb = xs + b * 512;
#pragma unroll
      for (int kk = 0; kk < 8; ++kk)
        acc[b] += dot4(*(const float4*)&xb[kk * 64 + ko * 4], w[kk]);
    }
#pragma unroll
    for (int b = 0; b < 32; ++b) {
      acc[b] += __shfl_xor(acc[b], 1);
      acc[b] += __shfl_xor(acc[b], 2);
      acc[b] += __shfl_xor(acc[b], 4);
      acc[b] += __shfl_xor(acc[b], 8);
    }
    if (ko == 0) {
      float bias = bq[j];
      for (int b = 0; b < 32; ++b)
        q[(lg * 32 + b) * H + j] = tanhf(acc[b] + bias);
    }
  }
}

__global__ __launch_bounds__(256) void sattn_kernel(
    const float* __restrict__ q, const float* __restrict__ keysT,
    const float* __restrict__ valuesT, const float* __restrict__ hmid,
    float* __restrict__ cat) {
  __shared__ __align__(16) float qv[528];
  __shared__ float scl[64];
  __shared__ float wts[64];
  int lb = blockIdx.x, tid = threadIdx.x;
  int b = lb & 31;
  {
    int c0 = tid, c1 = tid + 256;
    qv[(c0 >> 7) * 132 + (c0 & 127)] = q[lb * H + c0];
    qv[(c1 >> 7) * 132 + (c1 & 127)] = q[lb * H + c1];
  }
  __syncthreads();
  int kq = tid & 3, sl = tid >> 2;
  float acc = 0.f;
  if (sl < S) {
    const float* kr = keysT + ((size_t)b * S + sl) * H + kq * 128;
    const float* qr = &qv[kq * 132];
    for (int k = 0; k < 128; k += 4)
      acc += dot4(*(const float4*)&qr[k], *(const float4*)&kr[k]);
  }
  acc += __shfl_xor(acc, 1);
  acc += __shfl_xor(acc, 2);
  if (kq == 0 && sl < S) scl[sl] = acc * (1.0f / 7.0f);
  __syncthreads();
  if (tid < 64) {
    float sc = (tid < S) ? scl[tid] : -3.4e38f;
    float m = sc;
    for (int o = 32; o > 0; o >>= 1) m = fmaxf(m, __shfl_xor(m, o));
    float e = (tid < S) ? expf(sc - m) : 0.f;
    float sum = e;
    for (int o = 32; o > 0; o >>= 1) sum += __shfl_xor(sum, o);
    if (tid < S) wts[tid] = e / sum;
  }
  __syncthreads();
  float acc0 = 0.f, acc1 = 0.f;
  for (int s = 0; s < S; ++s) {
    float w = wts[s];
    const float* vr = valuesT + ((size_t)b * S + s) * H;
    acc0 += w * vr[tid];
    acc1 += w * vr[tid + 256];
  }
  cat[lb * 1024 + tid] = acc0;
  cat[lb * 1024 + tid + 256] = acc1;
  cat[lb * 1024 + 512 + tid] = hmid[lb * H + tid];
  cat[lb * 1024 + 768 + tid] = hmid[lb * H + tid + 256];
}

}  // namespace

extern "C" void kernel_launch(void* const* d_in, const int* in_sizes, int n_in,
                              void* d_out, int out_size, void* d_ws, size_t ws_size,
                              hipStream_t stream) {
  (void)in_sizes; (void)n_in; (void)out_size;
  const float* chan   = (const float*)d_in[0];
  const float* pooled = (const float*)d_in[1];
  const float* embed  = (const float*)d_in[2];
  const float* Wq     = (const float*)d_in[3];
  const float* bq     = (const float*)d_in[4];
  const float* Wk     = (const float*)d_in[5];
  const float* bk     = (const float*)d_in[6];
  const float* Wv     = (const float*)d_in[7];
  const float* bv     = (const float*)d_in[8];
  const float* Wih    = (const float*)d_in[9];
  const float* Whh    = (const float*)d_in[10];
  const float* bih    = (const float*)d_in[11];
  const float* bhh    = (const float*)d_in[12];
  const float* projW  = (const float*)d_in[13];
  const float* projb  = (const float*)d_in[14];
  const float* hattW  = (const float*)d_in[15];
  const float* hattb  = (const float*)d_in[16];
  const int*   sos    = (const int*)d_in[17];

  float* out = (float*)d_out;
  float* ws  = (float*)d_ws;

  float* keysT   = ws;                        // B*S*512
  float* valuesT = keysT + B * S * 512;       // B*S*512
  float* emb     = valuesT + B * S * 512;     // B*H
  float* h       = emb + B * H;               // L*B*H
  float* c       = h + L * B * H;             // L*B*H
  float* hmid    = c + L * B * H;             // L*B*H
  float* cat     = hmid + L * B * H;          // L*B*1024
  float* q       = cat + L * B * 1024;        // L*B*H (fallback only)
  float* logits  = q + L * B * H;             // B*V   (fallback only)
  float* slog    = logits + B * V;            // T*B*V

  size_t base_floats = (size_t)(slog - ws);
  bool staged = ws_size >= (base_floats + (size_t)T * B * V) * sizeof(float);

  if (staged) {
    // ---- 77-dispatch path: setup + 19x(lstm,lstm,projsat[,hattarg]) + finalize
    setup_kernel<<<1009, 256, 0, stream>>>(chan, Wk, bk, Wv, bv, keysT, valuesT,
                                           pooled, embed, sos, emb, h, c,
                                           projW, projb, slog);
    for (int t = 0; t < T - 1; ++t) {
      float* dst = slog + (size_t)(t + 1) * B * V;
      lstm_kernel<<<512, 256, 0, stream>>>(emb, h, c, Wih, Whh, bih, bhh, hmid, c);
      lstm_kernel<<<512, 256, 0, stream>>>(hmid, h + B * H, c + B * H,
                                           Wih + 4 * H * H, Whh + 4 * H * H,
                                           bih + 4 * H, bhh + 4 * H,
                                           hmid + B * H, c + B * H);
      bool last = (t == T - 2);
      projsat_kernel<<<last ? 625 : 689, 256, 0, stream>>>(
          hmid, projW, projb, Wq, bq, keysT, valuesT, dst, cat);
      if (!last)
        hattarg_kernel<<<160, 256, 0, stream>>>(cat, hattW, hattb, h,
                                                dst, embed, emb);
    }
    finalize_kernel<<<(B * V) / 256, 256, 0, stream>>>(slog, out);
    return;
  }

  // -------- fallback: verified 5-dispatch/step path (direct out writes) -----
  kv_kernel<<<256, 256, 0, stream>>>(chan, Wk, bk, Wv, bv, keysT, valuesT);
  init_kernel<<<(L * B * H) / 256, 256, 0, stream>>>(pooled, embed, sos, emb, h, c);
  projq_kernel<<<625, 256, 0, stream>>>(emb, projW, projb, logits, out,
                                        1, 0, hmid, Wq, bq, q);
  for (int t = 0; t < T - 1; ++t) {
    lstm_kernel<<<512, 256, 0, stream>>>(emb, h, c, Wih, Whh, bih, bhh, hmid, c);
    lstm_kernel<<<512, 256, 0, stream>>>(hmid, h + B * H, c + B * H,
                                         Wih + 4 * H * H, Whh + 4 * H * H,
                                         bih + 4 * H, bhh + 4 * H,
                                         hmid + B * H, c + B * H);
    projq_kernel<<<689, 256, 0, stream>>>(hmid + B * H, projW, projb, logits, out,
                                          1, t + 1, hmid, Wq, bq, q);
    sattn_kernel<<<L * B, 256, 0, stream>>>(q, keysT, valuesT, hmid, cat);
    hattarg_kernel<<<160, 256, 0, stream>>>(cat, hattW, hattb, h,
                                            logits, embed, emb);
  }
}